// Round 6
// baseline (473.644 us; speedup 1.0000x reference)
//
#include <hip/hip_runtime.h>

#define D_IN_C 16
#define D_OUT_C 32
#define NB_LOG 6                 // 64 nodes per bucket
#define NB (1 << NB_LOG)         // 64
#define NB_MASK (NB - 1)
#define MAXBUCK 1600             // supports up to 102400 nodes
#define EPB 12800                // edges per block in hist/bin

// ---------------------------------------------------------------------------
// K1: h = relu(x@w1+b1)@w2+b2 ; zero bucket counts (new path) or
// summed/cnt (fallback path).
// ---------------------------------------------------------------------------
__global__ __launch_bounds__(256) void mlp_kernel(
    const float* __restrict__ x,
    const float* __restrict__ w1, const float* __restrict__ b1,
    const float* __restrict__ w2, const float* __restrict__ b2,
    float* __restrict__ h, float* __restrict__ summed, int* __restrict__ cnt,
    int* __restrict__ gcount, int nbuck, int n_nodes) {
  __shared__ float sw1[256];
  __shared__ float sw2[256];
  __shared__ float sb1[16];
  __shared__ float sb2[16];
  int t = threadIdx.x;
  sw1[t] = w1[t];
  sw2[t] = w2[t];
  if (t < 16) { sb1[t] = b1[t]; sb2[t] = b2[t]; }
  __syncthreads();

  int n = blockIdx.x * blockDim.x + t;

  if (gcount && n < nbuck) gcount[n] = 0;
  if (n >= n_nodes) return;

  float xi[16];
  const float4* xr = (const float4*)(x + (size_t)n * 16);
  float4 v0 = xr[0], v1 = xr[1], v2 = xr[2], v3 = xr[3];
  xi[0]=v0.x; xi[1]=v0.y; xi[2]=v0.z; xi[3]=v0.w;
  xi[4]=v1.x; xi[5]=v1.y; xi[6]=v1.z; xi[7]=v1.w;
  xi[8]=v2.x; xi[9]=v2.y; xi[10]=v2.z; xi[11]=v2.w;
  xi[12]=v3.x; xi[13]=v3.y; xi[14]=v3.z; xi[15]=v3.w;

  float t1[16];
#pragma unroll
  for (int j = 0; j < 16; ++j) {
    float acc = sb1[j];
#pragma unroll
    for (int k = 0; k < 16; ++k) acc += xi[k] * sw1[k * 16 + j];
    t1[j] = fmaxf(acc, 0.0f);
  }
  float hh[16];
#pragma unroll
  for (int j = 0; j < 16; ++j) {
    float acc = sb2[j];
#pragma unroll
    for (int k = 0; k < 16; ++k) acc += t1[k] * sw2[k * 16 + j];
    hh[j] = acc;
  }

  float4* hw = (float4*)(h + (size_t)n * 16);
  hw[0] = make_float4(hh[0], hh[1], hh[2], hh[3]);
  hw[1] = make_float4(hh[4], hh[5], hh[6], hh[7]);
  hw[2] = make_float4(hh[8], hh[9], hh[10], hh[11]);
  hw[3] = make_float4(hh[12], hh[13], hh[14], hh[15]);

  if (cnt) cnt[n] = 0;
  if (summed) {
    float4* sz = (float4*)(summed + (size_t)n * 16);
    float4 z = make_float4(0.f, 0.f, 0.f, 0.f);
    sz[0] = z; sz[1] = z; sz[2] = z; sz[3] = z;
  }
}

// ---------------------------------------------------------------------------
// K2: per-bucket histogram, LDS-aggregated per block.
// ---------------------------------------------------------------------------
__global__ __launch_bounds__(1024) void hist_kernel(
    const int* __restrict__ dst, int* __restrict__ gcount,
    int nbuck, int n_edges) {
  __shared__ int lcnt[MAXBUCK];
  int t = threadIdx.x;
  for (int i = t; i < MAXBUCK; i += 1024) lcnt[i] = 0;
  __syncthreads();
  int e0 = blockIdx.x * EPB;
  int e1 = e0 + EPB; if (e1 > n_edges) e1 = n_edges;
  for (int e = e0 + t; e < e1; e += 1024)
    atomicAdd(&lcnt[dst[e] >> NB_LOG], 1);
  __syncthreads();
  for (int b = t; b < nbuck; b += 1024) {
    int c = lcnt[b];
    if (c) atomicAdd(&gcount[b], c);
  }
}

// ---------------------------------------------------------------------------
// K3: single-block exclusive scan over nbuck bucket counts.
// ---------------------------------------------------------------------------
__global__ __launch_bounds__(256) void scan_kernel(
    const int* __restrict__ gcount, int* __restrict__ base,
    int* __restrict__ cursor, int nbuck) {
  __shared__ int ps[256];
  int t = threadIdx.x;
  int per = (nbuck + 255) / 256;
  int beg = t * per;
  int end = beg + per; if (end > nbuck) end = nbuck;
  int sum = 0;
  for (int i = beg; i < end; ++i) sum += gcount[i];
  ps[t] = sum;
  __syncthreads();
#pragma unroll
  for (int off = 1; off < 256; off <<= 1) {
    int add = (t >= off) ? ps[t - off] : 0;
    __syncthreads();
    ps[t] += add;
    __syncthreads();
  }
  int run = ps[t] - sum;  // exclusive prefix
  for (int i = beg; i < end; ++i) {
    base[i] = run;
    cursor[i] = run;
    run += gcount[i];
  }
  if (t == 255) base[nbuck] = ps[255];
}

// ---------------------------------------------------------------------------
// K4: bin edges. Per block: LDS count -> span reservation -> LDS-rank
// scatter. pack = (src << 6) | (dst & 63)
// ---------------------------------------------------------------------------
__global__ __launch_bounds__(1024) void bin_kernel(
    const int* __restrict__ src, const int* __restrict__ dst,
    int* __restrict__ cursor, unsigned int* __restrict__ ebuf,
    int nbuck, int n_edges) {
  __shared__ int lcnt[MAXBUCK];
  __shared__ int lspan[MAXBUCK];
  int t = threadIdx.x;
  for (int i = t; i < MAXBUCK; i += 1024) lcnt[i] = 0;
  __syncthreads();
  int e0 = blockIdx.x * EPB;
  int e1 = e0 + EPB; if (e1 > n_edges) e1 = n_edges;
  // phase A: local count
  for (int e = e0 + t; e < e1; e += 1024)
    atomicAdd(&lcnt[dst[e] >> NB_LOG], 1);
  __syncthreads();
  // phase B: reserve spans, reset counters for rank pass
  for (int b = t; b < nbuck; b += 1024) {
    int c = lcnt[b];
    lspan[b] = c ? atomicAdd(&cursor[b], c) : 0;
    lcnt[b] = 0;
  }
  __syncthreads();
  // phase C: scatter
  for (int e = e0 + t; e < e1; e += 1024) {
    int d = dst[e];
    int b = d >> NB_LOG;
    int r = atomicAdd(&lcnt[b], 1);
    ebuf[lspan[b] + r] =
        ((unsigned int)src[e] << NB_LOG) | (unsigned int)(d & NB_MASK);
  }
}

// ---------------------------------------------------------------------------
// K5: per-bucket aggregate into LDS + fused SAGE epilogue.
// COOPERATIVE rows, UNIFORM ebuf reads, ZERO DS ops in the address chain.
//   - 16-lane group per edge; all lanes read the SAME packed entry
//     (broadcast load, ~2 transactions/wave-inst) — replaces round-4's
//     ds_bpermute, whose lgkmcnt coupling serialized the gathers.
//   - h-row read cooperatively: lane k loads h[s*16+k] -> 1 line per edge
//     (4 transactions/wave-inst) — vs round-5's row-per-lane, where each
//     wave-load touched 64 distinct lines (51.2M transactions = the
//     measured 314us). Gather transactions drop ~10x.
//   - U=8 edges unrolled with named scalars: 8 ebuf + 8 h loads
//     independently in flight per group.
// ---------------------------------------------------------------------------
__global__ __launch_bounds__(256) void agg_out_kernel(
    const float* __restrict__ h, const unsigned int* __restrict__ ebuf,
    const int* __restrict__ base,
    const float* __restrict__ wl, const float* __restrict__ bl,
    const float* __restrict__ wr, float* __restrict__ out, int n_nodes) {
  __shared__ float ssum[NB * 16];   // 4 KB
  __shared__ int   scnt[NB];
  __shared__ float swl[512];
  __shared__ float swr[512];
  __shared__ float sbl[32];

  int t = threadIdx.x;
  int b = blockIdx.x;

  for (int i = t; i < 512; i += 256) { swl[i] = wl[i]; swr[i] = wr[i]; }
  if (t < 32) sbl[t] = bl[t];
#pragma unroll
  for (int i = t; i < NB * 16; i += 256) ssum[i] = 0.0f;
  if (t < NB) scnt[t] = 0;
  __syncthreads();

  int beg = base[b];
  int end = base[b + 1];

  int g = t >> 4;        // 16 groups of 16 lanes
  int k = t & 15;

  for (int p0 = beg + g * 8; p0 < end; p0 += 128) {
    int m = end - p0; if (m > 8) m = 8;
    if (m == 8) {
      // 8 uniform entry loads (independent, all in flight)
      unsigned int e0 = ebuf[p0 + 0], e1 = ebuf[p0 + 1];
      unsigned int e2 = ebuf[p0 + 2], e3 = ebuf[p0 + 3];
      unsigned int e4 = ebuf[p0 + 4], e5 = ebuf[p0 + 5];
      unsigned int e6 = ebuf[p0 + 6], e7 = ebuf[p0 + 7];
      // 8 cooperative row loads (1 line each, independent)
      float v0 = h[(size_t)(e0 >> NB_LOG) * 16 + k];
      float v1 = h[(size_t)(e1 >> NB_LOG) * 16 + k];
      float v2 = h[(size_t)(e2 >> NB_LOG) * 16 + k];
      float v3 = h[(size_t)(e3 >> NB_LOG) * 16 + k];
      float v4 = h[(size_t)(e4 >> NB_LOG) * 16 + k];
      float v5 = h[(size_t)(e5 >> NB_LOG) * 16 + k];
      float v6 = h[(size_t)(e6 >> NB_LOG) * 16 + k];
      float v7 = h[(size_t)(e7 >> NB_LOG) * 16 + k];
      atomicAdd(&ssum[(e0 & NB_MASK) * 16 + k], v0);
      atomicAdd(&ssum[(e1 & NB_MASK) * 16 + k], v1);
      atomicAdd(&ssum[(e2 & NB_MASK) * 16 + k], v2);
      atomicAdd(&ssum[(e3 & NB_MASK) * 16 + k], v3);
      atomicAdd(&ssum[(e4 & NB_MASK) * 16 + k], v4);
      atomicAdd(&ssum[(e5 & NB_MASK) * 16 + k], v5);
      atomicAdd(&ssum[(e6 & NB_MASK) * 16 + k], v6);
      atomicAdd(&ssum[(e7 & NB_MASK) * 16 + k], v7);
      if (k == 0) {
        atomicAdd(&scnt[e0 & NB_MASK], 1);
        atomicAdd(&scnt[e1 & NB_MASK], 1);
        atomicAdd(&scnt[e2 & NB_MASK], 1);
        atomicAdd(&scnt[e3 & NB_MASK], 1);
        atomicAdd(&scnt[e4 & NB_MASK], 1);
        atomicAdd(&scnt[e5 & NB_MASK], 1);
        atomicAdd(&scnt[e6 & NB_MASK], 1);
        atomicAdd(&scnt[e7 & NB_MASK], 1);
      }
    } else {
      for (int u = 0; u < m; ++u) {
        unsigned int ee = ebuf[p0 + u];
        float v = h[(size_t)(ee >> NB_LOG) * 16 + k];
        atomicAdd(&ssum[(ee & NB_MASK) * 16 + k], v);
        if (k == 0) atomicAdd(&scnt[ee & NB_MASK], 1);
      }
    }
  }
  __syncthreads();

  // epilogue: out = mean @ wl + bl + h @ wr for the 64 nodes of this bucket
  int j = t & 31;
  for (int nl = t >> 5; nl < NB; nl += 8) {
    int n = b * NB + nl;
    if (n >= n_nodes) break;
    float inv = 1.0f / fmaxf((float)scnt[nl], 1.0f);
    float acc = sbl[j];
    const float* hr = h + (size_t)n * 16;
#pragma unroll
    for (int kk = 0; kk < 16; ++kk) {
      float mv = ssum[nl * 16 + kk] * inv;
      acc += mv * swl[kk * 32 + j] + hr[kk] * swr[kk * 32 + j];
    }
    out[(size_t)n * 32 + j] = acc;
  }
}

// ---------------------------------------------------------------------------
// FALLBACK PATH (verified atomic kernels) — used only if ws too small or
// bucket table exceeds MAXBUCK.
// ---------------------------------------------------------------------------
__global__ __launch_bounds__(256) void scatter_kernel(
    const int* __restrict__ src, const int* __restrict__ dst,
    const float* __restrict__ h, float* __restrict__ summed,
    int* __restrict__ cnt, long long n_edges) {
  long long tid = (long long)blockIdx.x * blockDim.x + threadIdx.x;
  long long e = tid >> 4;
  int k = (int)(tid & 15);
  if (e >= n_edges) return;
  int s = src[e];
  int d = dst[e];
  float val = h[(size_t)s * 16 + k];
  atomicAdd(&summed[(size_t)d * 16 + k], val);
  if (k == 0) atomicAdd(&cnt[d], 1);
}

__global__ __launch_bounds__(256) void out_kernel(
    const float* __restrict__ h, const float* __restrict__ summed,
    const int* __restrict__ cnt,
    const float* __restrict__ wl, const float* __restrict__ bl,
    const float* __restrict__ wr, float* __restrict__ out, int n_nodes) {
  __shared__ float swl[512];
  __shared__ float swr[512];
  __shared__ float sbl[32];
  int t = threadIdx.x;
  for (int i = t; i < 512; i += 256) { swl[i] = wl[i]; swr[i] = wr[i]; }
  if (t < 32) sbl[t] = bl[t];
  __syncthreads();

  int gid = blockIdx.x * 256 + t;
  int n = gid >> 5;
  int j = gid & 31;
  if (n >= n_nodes) return;

  float inv = 1.0f / fmaxf((float)cnt[n], 1.0f);
  const float* hr = h + (size_t)n * 16;
  const float* sr = summed + (size_t)n * 16;
  float acc = sbl[j];
#pragma unroll
  for (int k = 0; k < 16; ++k) {
    acc += sr[k] * inv * swl[k * 32 + j] + hr[k] * swr[k * 32 + j];
  }
  out[(size_t)n * 32 + j] = acc;
}

// ---------------------------------------------------------------------------
extern "C" void kernel_launch(void* const* d_in, const int* in_sizes, int n_in,
                              void* d_out, int out_size, void* d_ws, size_t ws_size,
                              hipStream_t stream) {
  const float* x  = (const float*)d_in[0];
  const int* eidx = (const int*)d_in[1];
  const float* w1 = (const float*)d_in[2];
  const float* b1 = (const float*)d_in[3];
  const float* w2 = (const float*)d_in[4];
  const float* b2 = (const float*)d_in[5];
  const float* wl = (const float*)d_in[6];
  const float* bl = (const float*)d_in[7];
  const float* wr = (const float*)d_in[8];
  float* out = (float*)d_out;

  const int n_nodes = in_sizes[0] / D_IN_C;             // 100000
  const long long n_edges = (long long)in_sizes[1] / 2; // 3200000
  const int* src = eidx;
  const int* dst = eidx + n_edges;

  const int node_blocks = (n_nodes + 255) / 256;         // 391
  const int nbuck = (n_nodes + NB - 1) / NB;             // 1563
  const int epb_blocks = (int)((n_edges + EPB - 1) / EPB); // 250

  // New-path workspace layout.
  float*        h      = (float*)d_ws;                       // N*16 f32
  int*          gcount = (int*)(h + (size_t)n_nodes * 16);   // nbuck
  int*          cursor = gcount + nbuck;                     // nbuck
  int*          base   = cursor + nbuck;                     // nbuck+1
  unsigned int* ebuf   = (unsigned int*)(base + nbuck + 1);  // E u32

  size_t need = ((size_t)n_nodes * 16 + 3ull * nbuck + 1 + (size_t)n_edges) * 4;

  if (ws_size >= need && nbuck <= MAXBUCK) {
    // ---- coarse-bucket counting sort + LDS aggregation ----
    mlp_kernel<<<node_blocks, 256, 0, stream>>>(
        x, w1, b1, w2, b2, h, nullptr, nullptr, gcount, nbuck, n_nodes);
    hist_kernel<<<epb_blocks, 1024, 0, stream>>>(dst, gcount, nbuck, (int)n_edges);
    scan_kernel<<<1, 256, 0, stream>>>(gcount, base, cursor, nbuck);
    bin_kernel<<<epb_blocks, 1024, 0, stream>>>(src, dst, cursor, ebuf,
                                                nbuck, (int)n_edges);
    agg_out_kernel<<<nbuck, 256, 0, stream>>>(h, ebuf, base, wl, bl, wr, out,
                                              n_nodes);
  } else {
    // ---- fallback: verified atomic path ----
    float* summed = h + (size_t)n_nodes * 16;
    int*   fcnt   = (int*)(summed + (size_t)n_nodes * 16);
    mlp_kernel<<<node_blocks, 256, 0, stream>>>(
        x, w1, b1, w2, b2, h, summed, fcnt, nullptr, 0, n_nodes);
    {
      long long total = n_edges * 16;
      int blocks = (int)((total + 255) / 256);
      scatter_kernel<<<blocks, 256, 0, stream>>>(src, dst, h, summed, fcnt, n_edges);
    }
    {
      long long total = (long long)n_nodes * 32;
      int blocks = (int)((total + 255) / 256);
      out_kernel<<<blocks, 256, 0, stream>>>(h, summed, fcnt, wl, bl, wr, out, n_nodes);
    }
  }
}